// Round 6
// baseline (316.050 us; speedup 1.0000x reference)
//
#include <hip/hip_runtime.h>

#define N_NODES 50000
#define N_EDGES 800000
#define K_BR    8
#define BCAP    131072           // per-bucket slot capacity (2^17); mean fill 100K
#define MLP_SLOTS (K_BR * BCAP)  // 1,048,576
#define SCAN_BLOCKS 196          // ceil(50000/256)
#define BSTRIDE 1024             // bucketCur stride in ints (R1: null, kept)
#define EPT 8                    // pass1 edges/thread (R3 structure)
#define P1_BLOCKS 391            // ceil(800000 / 2048)
#define RB 128                   // rank blocks
#define RBE 6250                 // edges per rank block (128*6250 = 800000 exactly)

// R6: MEASUREMENT ROUND. Totals were invariant (196-204us) across R1-R5 while
// per-kernel wins landed (pass1 53us -> <42us). Our latency models say our six
// kernels sum to ~40us, yet total is ~200us; the profile top-5 is all harness
// 268MB poison fills (42us each) and hides our kernels entirely. To split
// "our kernels" from "harness constant (fills + ~18 dispatches of replay
// overhead)", this round runs the ENTIRE idempotent pipeline TWICE:
//   kernels_sum = total(R6) - total(R5);  C = total(R5) - kernels_sum.
// All kernels are idempotent given a re-zeroed bucketCur (second memset).

typedef _Float16 h2 __attribute__((ext_vector_type(2)));
typedef _Float16 half8 __attribute__((ext_vector_type(8)));
typedef float f32x4 __attribute__((ext_vector_type(4)));

#define MFMA(a, b, c) __builtin_amdgcn_mfma_f32_16x16x32_f16((a), (b), (c), 0, 0, 0)

#define VAL_MASK 0x3FFFFFFFu
#define FLG_A    0x40000000u
#define FLG_P    0x80000000u

// ---------------- workspace layout (bytes) ----------------
// fbuf      : 800,000 x 64 B f16         @ 0           (51,200,000)
// payload   : MLP_SLOTS x 16 B           @ 51,200,000  (16,777,216)
// cnt(deg)  : N ints                     @ 67,977,216  (200,000)  [written by colscan]
// bucketCur : 8 ints @ 4KB stride        @ 68,177,216  (32,768)   [memset 0]
// ps        : 196 uints (lookback)       @ 68,209,984  (800)      [memset 0]
// nodeStart : N ints                     @ 68,210,816  (200,000)
// w1f4      : 2048 uint4 (B-frags L1)    @ 68,410,816  (32,768)
// w2f4      : 1024 uint4 (B-frags L2)    @ 68,443,584  (16,384)
// xh        : 50,000 x 32 f16            @ 68,459,968  (3,200,000)
// rankB     : E u16 (rank within block)  @ 71,659,968  (1,600,000)
// cntM      : [128][50000] u16           @ 73,259,968  (12,800,000)
// blkBase   : [128][50000] u16           @ 86,059,968  (12,800,000)
// total: 98,859,968  (< proven ws floor 109,473,920)

__device__ __forceinline__ int branch_idx(float dx, float dy) {
    return (dx > 0.0f ? 1 : 0) + (dy > 0.0f ? 2 : 0) +
           ((fabsf(dx) - fabsf(dy)) > 0.0f ? 4 : 0);
}

__device__ __forceinline__ unsigned pk_f16pair(float a, float b) {
    h2 p; p.x = (_Float16)a; p.y = (_Float16)b;
    return __builtin_bit_cast(unsigned, p);
}

__device__ __forceinline__ unsigned short f16bits(float a) {
    _Float16 h = (_Float16)a;
    return __builtin_bit_cast(unsigned short, h);
}

// Per-block node histogram + per-edge rank, NO device atomics.
// LDS: 25K u32 = two u16 counters per word (even d low, odd d high).
// Also absorbs x->f16 mirror and W-frag packing (moved from pass1).
__global__ void __launch_bounds__(256) rank_kernel(
    const int* __restrict__ ei, const float* __restrict__ x,
    const float* __restrict__ W1, const float* __restrict__ W2,
    unsigned short* __restrict__ rankB, unsigned short* __restrict__ cntM,
    unsigned* __restrict__ xh, uint4* __restrict__ w1f4, uint4* __restrict__ w2f4) {
    __shared__ unsigned hist[N_NODES / 2];   // 100,000 B
    int t = threadIdx.x, b = blockIdx.x;
    for (int i = t; i < N_NODES / 2; i += 256) hist[i] = 0;

    // W fragments (global tid < 3072)
    int tid = b * 256 + t;
    if (tid < 2048) {                         // layer-1 B frags
        int L = tid & 63, fl = tid >> 6;
        int nt = fl & 1, kt = (fl >> 1) & 1, k = fl >> 2;
        int quad = L >> 4, col = L & 15;
        unsigned dw[4];
#pragma unroll
        for (int i = 0; i < 4; ++i) {
            float v0 = 0.0f, v1 = 0.0f;
            int k0 = kt * 32 + quad * 8 + 2 * i;
            if (k0 < 36)     v0 = W1[k * 1152 + k0 * 32 + nt * 16 + col];
            if (k0 + 1 < 36) v1 = W1[k * 1152 + (k0 + 1) * 32 + nt * 16 + col];
            dw[i] = pk_f16pair(v0, v1);
        }
        w1f4[tid] = make_uint4(dw[0], dw[1], dw[2], dw[3]);
    } else if (tid < 3072) {                  // layer-2 B frags
        int u2 = tid - 2048;
        int L = u2 & 63, fl = u2 >> 6;
        int nt = fl & 1, k = fl >> 1;
        int quad = L >> 4, col = L & 15;
        unsigned dw[4];
#pragma unroll
        for (int i = 0; i < 4; ++i) {
            int k0 = quad * 8 + 2 * i;
            dw[i] = pk_f16pair(W2[k * 1024 + k0 * 32 + nt * 16 + col],
                               W2[k * 1024 + (k0 + 1) * 32 + nt * 16 + col]);
        }
        w2f4[u2] = make_uint4(dw[0], dw[1], dw[2], dw[3]);
    }

    __syncthreads();
    int eb = b * RBE;
    for (int it = 0; it < (RBE + 255) / 256; ++it) {
        int r = it * 256 + t;
        if (r < RBE) {
            int e = eb + r;
            int d = ei[N_EDGES + e];
            unsigned add = (d & 1) ? (1u << 16) : 1u;
            unsigned old = atomicAdd(&hist[d >> 1], add);
            unsigned rk = (d & 1) ? (old >> 16) : (old & 0xFFFFu);
            rankB[e] = (unsigned short)rk;
            // x mirror: e covers all 800K float2 of x exactly once
            float2 xv = ((const float2*)x)[e];
            xh[e] = pk_f16pair(xv.x, xv.y);
        }
    }
    __syncthreads();
    // dump histogram row (u32 word i = counts for d=2i (lo), d=2i+1 (hi))
    unsigned* cm = (unsigned*)(cntM + (size_t)b * N_NODES);
    for (int i = t; i < N_NODES / 2; i += 256) cm[i] = hist[i];
}

// Per-node exclusive prefix over the 128 block counts -> blkBase, cnt(=deg).
__global__ void colscan_kernel(const unsigned short* __restrict__ cntM,
                               unsigned short* __restrict__ blkBase,
                               int* __restrict__ cnt) {
    int d = blockIdx.x * 256 + threadIdx.x;
    if (d >= N_NODES) return;
    int acc = 0;
#pragma unroll 8
    for (int b = 0; b < RB; ++b) {
        size_t i = (size_t)b * N_NODES + d;
        int v = cntM[i];
        blkBase[i] = (unsigned short)acc;
        acc += v;
    }
    cnt[d] = acc;
}

// Edge pass: branch histogram + bucket scatter of packed 16B payload.
// slotLocal = blkBase[e/RBE][d] + rankB[e]  (no device atomics).
__global__ void pass1_kernel(const int* __restrict__ ei, const float* __restrict__ pos,
                             const float* __restrict__ ea, const float* __restrict__ ew,
                             const unsigned short* __restrict__ rankB,
                             const unsigned short* __restrict__ blkBase,
                             int* __restrict__ bucketCur,
                             uint4* __restrict__ payload) {
    __shared__ int h[K_BR];
    __shared__ int base[K_BR];
    int t = threadIdx.x;
    if (t < K_BR) h[t] = 0;
    __syncthreads();

    int eBase = blockIdx.x * (256 * EPT);
    int sA[EPT], dA[EPT], krA[EPT], slA[EPT];
#pragma unroll
    for (int it = 0; it < EPT; ++it) {
        int e = eBase + it * 256 + t;        // coalesced per sub-iteration
        int s = 0, d = 0, k = 0, rank = 0, slot = 0;
        if (e < N_EDGES) {
            s = ei[e]; d = ei[N_EDGES + e];
            float2 ps2 = ((const float2*)pos)[s];
            float2 pd2 = ((const float2*)pos)[d];
            k = branch_idx(ps2.x - pd2.x, ps2.y - pd2.y);
            rank = atomicAdd(&h[k], 1);
            int bb = e / RBE;
            slot = (int)blkBase[(size_t)bb * N_NODES + d] + (int)rankB[e];
        }
        sA[it] = s; dA[it] = d; krA[it] = (k << 16) | rank; slA[it] = slot;
    }
    __syncthreads();
    if (t < K_BR) base[t] = (h[t] > 0) ? atomicAdd(&bucketCur[t * BSTRIDE], h[t]) : 0;
    __syncthreads();
#pragma unroll
    for (int it = 0; it < EPT; ++it) {
        int e = eBase + it * 256 + t;
        if (e < N_EDGES) {
            int k = krA[it] >> 16, rank = krA[it] & 0xFFFF;
            float4 eav = ((const float4*)ea)[e];
            unsigned ewh = (unsigned)f16bits(ew[e]);
            int idx = (k << 17) + base[k] + rank;
            payload[idx] = make_uint4((unsigned)sA[it] | ((unsigned)dA[it] << 16),
                                      (unsigned)slA[it] | (ewh << 16),
                                      pk_f16pair(eav.x, eav.y),
                                      pk_f16pair(eav.z, eav.w));
        }
    }
}

// single-dispatch decoupled-lookback exclusive scan (R11-proven).
__global__ void scan_kernel(const int* __restrict__ cnt, unsigned* __restrict__ ps,
                            int* __restrict__ nodeStart) {
    __shared__ int s[256];
    __shared__ int sh_off;
    int t = threadIdx.x, b = blockIdx.x;
    int i = b * 256 + t;
    int v = (i < N_NODES) ? cnt[i] : 0;
    s[t] = v;
    __syncthreads();
#pragma unroll
    for (int off = 1; off < 256; off <<= 1) {
        int tmp = (t >= off) ? s[t - off] : 0;
        __syncthreads();
        s[t] += tmp;
        __syncthreads();
    }
    int excl = s[t] - v;
    if (t == 255)
        atomicExch(&ps[b], (unsigned)s[255] | (b == 0 ? FLG_P : FLG_A));
    if (t == 0) sh_off = 0;
    if (t < 64 && b > 0) {   // wave-parallel lookback in wave 0
        int off = 0;
        int base = b - 1;
        for (;;) {
            int idx = base - t;
            unsigned w = 0;
            if (idx >= 0) {
                do { w = atomicOr(&ps[idx], 0u); } while (!(w & (FLG_A | FLG_P)));
            }
            bool isP = (w & FLG_P) != 0;
            unsigned long long pm = __ballot(isP);
            int firstP = pm ? (__ffsll((unsigned long long)pm) - 1) : 64;
            int contrib = (idx >= 0 && t <= firstP) ? (int)(w & VAL_MASK) : 0;
#pragma unroll
            for (int sh = 32; sh > 0; sh >>= 1) contrib += __shfl_down(contrib, sh, 64);
            contrib = __shfl(contrib, 0, 64);
            off += contrib;
            if (firstP < 64 || base - 64 < 0) break;
            base -= 64;
        }
        if (t == 0) sh_off = off;
    }
    __syncthreads();
    if (i < N_NODES) nodeStart[i] = excl + sh_off;
}

// MFMA MLP (R12-verified layouts). R14: 64-thread single-wave blocks ->
// LDS 10,496 B/block -> 15 blocks = 15 waves/CU.
__global__ void __launch_bounds__(64) mlp_kernel(
    const uint4* __restrict__ payload,
    const unsigned* __restrict__ xh,
    const uint4* __restrict__ w1f4, const float* __restrict__ b1,
    const uint4* __restrict__ w2f4, const float* __restrict__ b2,
    const int* __restrict__ nodeStart,
    const int* __restrict__ bucketFill,
    unsigned short* __restrict__ fbuf) {
    // m = 64 rows x 144B (9216) + h = 16 rows x 80B (1280) = 10,496 B
    __shared__ uint4 lds4[656];
    char* mreg = (char*)lds4;
    char* hreg = mreg + 9216;

    int t = blockIdx.x * 64 + threadIdx.x;
    int u = __builtin_amdgcn_readfirstlane(t);
    int k = u >> 17;
    int fill = bucketFill[k * BSTRIDE];
    if ((u & (BCAP - 1)) >= fill) return;   // whole wave past bucket fill
    int rel = t & (BCAP - 1);
    bool valid = rel < fill;
    int idx = (k << 17) + min(rel, fill - 1);  // clamp: pad slots are garbage

    int L = threadIdx.x;
    int quad = L >> 4, col = L & 15;

    uint4 pl = payload[idx];
    int s = (int)(pl.x & 0xFFFFu);
    int d = (int)(pl.x >> 16);
    _Float16 wh = __builtin_bit_cast(_Float16, (unsigned short)(pl.y >> 16));
    int slot = valid ? (nodeStart[d] + (int)(pl.y & 0xFFFFu)) : 0;

    // ---- stage m (f16, zero-padded k=36..63): packed half8 subtract ----
    const uint4* xj = ((const uint4*)xh) + 4 * (size_t)s;   // 64B f16 row
    const uint4* xi = ((const uint4*)xh) + 4 * (size_t)d;
    uint4* mrow = (uint4*)(mreg + L * 144);
#pragma unroll
    for (int q = 0; q < 4; ++q) {
        half8 a8 = __builtin_bit_cast(half8, xj[q]);
        half8 b8 = __builtin_bit_cast(half8, xi[q]);
        half8 d8 = a8 - b8;
        mrow[q] = __builtin_bit_cast(uint4, d8);
    }
    mrow[4] = make_uint4(pl.z, pl.w, 0u, 0u);
    mrow[5] = make_uint4(0u, 0u, 0u, 0u);
    mrow[6] = make_uint4(0u, 0u, 0u, 0u);
    mrow[7] = make_uint4(0u, 0u, 0u, 0u);

    // ---- B fragments (held in VGPRs; coalesced 16B/lane loads) ----
    half8 B1[2][2], B2[2];
#pragma unroll
    for (int kt = 0; kt < 2; ++kt)
#pragma unroll
        for (int nt = 0; nt < 2; ++nt)
            B1[kt][nt] = __builtin_bit_cast(half8, w1f4[((k * 2 + kt) * 2 + nt) * 64 + L]);
#pragma unroll
    for (int nt = 0; nt < 2; ++nt)
        B2[nt] = __builtin_bit_cast(half8, w2f4[(k * 2 + nt) * 64 + L]);
    float b1o0 = b1[k * 32 + col],      b1o1 = b1[k * 32 + 16 + col];
    float b2o0 = b2[k * 32 + col],      b2o1 = b2[k * 32 + 16 + col];

#pragma unroll
    for (int mt = 0; mt < 4; ++mt) {
        int arow = mt * 16 + col;
        half8 a0 = __builtin_bit_cast(half8, *(const uint4*)(mreg + arow * 144 + quad * 16));
        half8 a1 = __builtin_bit_cast(half8, *(const uint4*)(mreg + arow * 144 + 64 + quad * 16));
        f32x4 c0 = {b1o0, b1o0, b1o0, b1o0};
        f32x4 c1 = {b1o1, b1o1, b1o1, b1o1};
        c0 = MFMA(a0, B1[0][0], c0);
        c0 = MFMA(a1, B1[1][0], c0);
        c1 = MFMA(a0, B1[0][1], c1);
        c1 = MFMA(a1, B1[1][1], c1);
        // ReLU -> per-mt h buffer (16 edges x 32 ch, f16); wave-synchronous
#pragma unroll
        for (int r = 0; r < 4; ++r) {
            int er = quad * 4 + r;
            *(unsigned short*)(hreg + er * 80 + col * 2)        = f16bits(fmaxf(c0[r], 0.0f));
            *(unsigned short*)(hreg + er * 80 + (16 + col) * 2) = f16bits(fmaxf(c1[r], 0.0f));
        }
        // layer 2 for this mt
        half8 ah = __builtin_bit_cast(half8, *(const uint4*)(hreg + col * 80 + quad * 16));
        f32x4 d0 = {b2o0, b2o0, b2o0, b2o0};
        f32x4 d1 = {b2o1, b2o1, b2o1, b2o1};
        d0 = MFMA(ah, B2[0], d0);
        d1 = MFMA(ah, B2[1], d1);
#pragma unroll
        for (int r = 0; r < 4; ++r) {
            int edge = mt * 16 + quad * 4 + r;
            *(unsigned short*)(mreg + edge * 144 + col * 2)        = f16bits(fmaxf(d0[r], 0.0f));
            *(unsigned short*)(mreg + edge * 144 + (16 + col) * 2) = f16bits(fmaxf(d1[r], 0.0f));
        }
    }

    // ---- read back own edge's out row, *w (packed f16), store 64B ----
    half8 w8 = {wh, wh, wh, wh, wh, wh, wh, wh};
    uint4* orow = (uint4*)(mreg + L * 144);
    uint4* frow = (uint4*)(fbuf + 32 * (size_t)slot);
#pragma unroll
    for (int q = 0; q < 4; ++q) {
        half8 v8 = __builtin_bit_cast(half8, orow[q]);
        v8 = v8 * w8;
        if (valid) frow[q] = __builtin_bit_cast(uint4, v8);
    }
}

// 4 channels per thread: uint2 read = 4 f16; 8 threads/node cover a 64B row.
__global__ void agg_kernel(const unsigned short* __restrict__ fbuf,
                           const int* __restrict__ nodeStart, const int* __restrict__ deg,
                           const float* __restrict__ x, const float* __restrict__ Wr,
                           const float* __restrict__ br, float* __restrict__ out) {
    int t = blockIdx.x * blockDim.x + threadIdx.x;
    if (t >= N_NODES * 8) return;
    int n = t >> 3, g8 = t & 7;          // channels 4*g8 .. 4*g8+3
    int st = nodeStart[n], dg = deg[n];
    const uint2* fb = (const uint2*)fbuf;
    float a0 = 0.0f, a1 = 0.0f, a2 = 0.0f, a3 = 0.0f;
    for (int j = 0; j < dg; ++j) {
        uint2 uu = fb[(size_t)(st + j) * 8 + g8];   // CSR-contiguous stream
        h2 p01 = __builtin_bit_cast(h2, uu.x);
        h2 p23 = __builtin_bit_cast(h2, uu.y);
        a0 += (float)p01.x;
        a1 += (float)p01.y;
        a2 += (float)p23.x;
        a3 += (float)p23.y;
    }
    float inv = 1.0f / (float)max(dg, 1);
    int o = g8 * 4;
    a0 = a0 * inv + br[o];
    a1 = a1 * inv + br[o + 1];
    a2 = a2 * inv + br[o + 2];
    a3 = a3 * inv + br[o + 3];
    const float* xr = x + 32 * (size_t)n;
#pragma unroll
    for (int c = 0; c < 32; ++c) {
        float xv = xr[c];
        a0 = fmaf(xv, Wr[c * 32 + o], a0);
        a1 = fmaf(xv, Wr[c * 32 + o + 1], a1);
        a2 = fmaf(xv, Wr[c * 32 + o + 2], a2);
        a3 = fmaf(xv, Wr[c * 32 + o + 3], a3);
    }
    float4* o4 = (float4*)(out + 32 * (size_t)n + o);
    *o4 = make_float4(a0, a1, a2, a3);
}

extern "C" void kernel_launch(void* const* d_in, const int* in_sizes, int n_in,
                              void* d_out, int out_size, void* d_ws, size_t ws_size,
                              hipStream_t stream) {
    const float* x   = (const float*)d_in[0];
    const float* pos = (const float*)d_in[1];
    const int*   ei  = (const int*)d_in[2];
    const float* ea  = (const float*)d_in[3];
    const float* ew  = (const float*)d_in[4];
    const float* W1  = (const float*)d_in[5];
    const float* b1  = (const float*)d_in[6];
    const float* W2  = (const float*)d_in[7];
    const float* b2  = (const float*)d_in[8];
    const float* Wr  = (const float*)d_in[9];
    const float* br  = (const float*)d_in[10];
    float* out = (float*)d_out;

    char* ws = (char*)d_ws;
    unsigned short* fbuf = (unsigned short*)(ws + 0);
    uint4* payload  = (uint4*)(ws + 51200000);
    int* cnt        = (int*)(ws + 67977216);
    int* bucketCur  = (int*)(ws + 68177216);   // 8 counters @ 4KB stride
    unsigned* psLb  = (unsigned*)(ws + 68209984);
    int* nodeStart  = (int*)(ws + 68210816);
    uint4* w1f4     = (uint4*)(ws + 68410816);
    uint4* w2f4     = (uint4*)(ws + 68443584);
    unsigned* xh    = (unsigned*)(ws + 68459968);
    unsigned short* rankB   = (unsigned short*)(ws + 71659968);
    unsigned short* cntM    = (unsigned short*)(ws + 73259968);
    unsigned short* blkBase = (unsigned short*)(ws + 86059968);

    // -------- run 1 --------
    hipMemsetAsync(bucketCur, 0, 33568, stream);  // bucketCur(strided) + ps
    rank_kernel<<<RB, 256, 0, stream>>>(ei, x, W1, W2, rankB, cntM, xh, w1f4, w2f4);
    colscan_kernel<<<SCAN_BLOCKS, 256, 0, stream>>>(cntM, blkBase, cnt);
    scan_kernel<<<SCAN_BLOCKS, 256, 0, stream>>>(cnt, psLb, nodeStart);
    pass1_kernel<<<P1_BLOCKS, 256, 0, stream>>>(ei, pos, ea, ew, rankB, blkBase,
                                                bucketCur, payload);
    mlp_kernel<<<MLP_SLOTS / 64, 64, 0, stream>>>(payload, xh, w1f4, b1, w2f4, b2,
                                                  nodeStart, bucketCur, fbuf);
    agg_kernel<<<(N_NODES * 8 + 255) / 256, 256, 0, stream>>>(fbuf, nodeStart, cnt,
                                                              x, Wr, br, out);

    // -------- run 2 (R6 probe: identical, idempotent; delta total = our cost) --------
    hipMemsetAsync(bucketCur, 0, 33568, stream);
    rank_kernel<<<RB, 256, 0, stream>>>(ei, x, W1, W2, rankB, cntM, xh, w1f4, w2f4);
    colscan_kernel<<<SCAN_BLOCKS, 256, 0, stream>>>(cntM, blkBase, cnt);
    scan_kernel<<<SCAN_BLOCKS, 256, 0, stream>>>(cnt, psLb, nodeStart);
    pass1_kernel<<<P1_BLOCKS, 256, 0, stream>>>(ei, pos, ea, ew, rankB, blkBase,
                                                bucketCur, payload);
    mlp_kernel<<<MLP_SLOTS / 64, 64, 0, stream>>>(payload, xh, w1f4, b1, w2f4, b2,
                                                  nodeStart, bucketCur, fbuf);
    agg_kernel<<<(N_NODES * 8 + 255) / 256, 256, 0, stream>>>(fbuf, nodeStart, cnt,
                                                              x, Wr, br, out);
}

// Round 7
// 189.866 us; speedup vs baseline: 1.6646x; 1.6646x over previous
//
#include <hip/hip_runtime.h>

#define N_NODES 50000
#define N_EDGES 800000
#define K_BR    8
#define BCAP    131072           // per-bucket slot capacity (2^17); mean fill 100K
#define MLP_SLOTS (K_BR * BCAP)  // 1,048,576
#define SCAN_BLOCKS 196          // ceil(50000/256)
#define BSTRIDE 1024             // bucketCur stride in ints (R1: null, kept)
#define EPT 8                    // pass1 edges/thread (R3 structure)
#define P1_BLOCKS 391            // ceil(800000 / 2048)
#define RB 128                   // rank blocks
#define RBE 6250                 // edges per rank block (128*6250 = 800000 exactly)

// R6 accounting (double-run probe): our pipeline = 112us, harness constant = 92us.
// mlp_kernel = 41.6us dominated: Occ 28%, Mfma 4%, HBM 29% -> latency-bound, LDS
// 10.75KB/wave capped residency at 15 waves/CU and the serial LDS chain was long.
// R7: mlp rewritten — A-frags gathered DIRECTLY from xh in MFMA layout (shfl the
// s/d/ea of the owner lane, 16B loads, packed sub), outputs stored DIRECTLY from
// accumulators (shfl slot/wh/valid). LDS = h-transpose only: 1,280B/wave.

typedef _Float16 h2 __attribute__((ext_vector_type(2)));
typedef _Float16 half8 __attribute__((ext_vector_type(8)));
typedef float f32x4 __attribute__((ext_vector_type(4)));

#define MFMA(a, b, c) __builtin_amdgcn_mfma_f32_16x16x32_f16((a), (b), (c), 0, 0, 0)

#define VAL_MASK 0x3FFFFFFFu
#define FLG_A    0x40000000u
#define FLG_P    0x80000000u

// ---------------- workspace layout (bytes) ----------------
// fbuf      : 800,000 x 64 B f16         @ 0           (51,200,000)
// payload   : MLP_SLOTS x 16 B           @ 51,200,000  (16,777,216)
// cnt(deg)  : N ints                     @ 67,977,216  (200,000)  [written by colscan]
// bucketCur : 8 ints @ 4KB stride        @ 68,177,216  (32,768)   [memset 0]
// ps        : 196 uints (lookback)       @ 68,209,984  (800)      [memset 0]
// nodeStart : N ints                     @ 68,210,816  (200,000)
// w1f4      : 2048 uint4 (B-frags L1)    @ 68,410,816  (32,768)
// w2f4      : 1024 uint4 (B-frags L2)    @ 68,443,584  (16,384)
// xh        : 50,000 x 32 f16            @ 68,459,968  (3,200,000)
// rankB     : E u16 (rank within block)  @ 71,659,968  (1,600,000)
// cntM      : [128][50000] u16           @ 73,259,968  (12,800,000)
// blkBase   : [128][50000] u16           @ 86,059,968  (12,800,000)
// total: 98,859,968  (< proven ws floor 109,473,920)

__device__ __forceinline__ int branch_idx(float dx, float dy) {
    return (dx > 0.0f ? 1 : 0) + (dy > 0.0f ? 2 : 0) +
           ((fabsf(dx) - fabsf(dy)) > 0.0f ? 4 : 0);
}

__device__ __forceinline__ unsigned pk_f16pair(float a, float b) {
    h2 p; p.x = (_Float16)a; p.y = (_Float16)b;
    return __builtin_bit_cast(unsigned, p);
}

__device__ __forceinline__ unsigned short f16bits(float a) {
    _Float16 h = (_Float16)a;
    return __builtin_bit_cast(unsigned short, h);
}

// Per-block node histogram + per-edge rank, NO device atomics.
// LDS: 25K u32 = two u16 counters per word (even d low, odd d high).
// Also absorbs x->f16 mirror and W-frag packing.
__global__ void __launch_bounds__(256) rank_kernel(
    const int* __restrict__ ei, const float* __restrict__ x,
    const float* __restrict__ W1, const float* __restrict__ W2,
    unsigned short* __restrict__ rankB, unsigned short* __restrict__ cntM,
    unsigned* __restrict__ xh, uint4* __restrict__ w1f4, uint4* __restrict__ w2f4) {
    __shared__ unsigned hist[N_NODES / 2];   // 100,000 B
    int t = threadIdx.x, b = blockIdx.x;
    for (int i = t; i < N_NODES / 2; i += 256) hist[i] = 0;

    // W fragments (global tid < 3072)
    int tid = b * 256 + t;
    if (tid < 2048) {                         // layer-1 B frags
        int L = tid & 63, fl = tid >> 6;
        int nt = fl & 1, kt = (fl >> 1) & 1, k = fl >> 2;
        int quad = L >> 4, col = L & 15;
        unsigned dw[4];
#pragma unroll
        for (int i = 0; i < 4; ++i) {
            float v0 = 0.0f, v1 = 0.0f;
            int k0 = kt * 32 + quad * 8 + 2 * i;
            if (k0 < 36)     v0 = W1[k * 1152 + k0 * 32 + nt * 16 + col];
            if (k0 + 1 < 36) v1 = W1[k * 1152 + (k0 + 1) * 32 + nt * 16 + col];
            dw[i] = pk_f16pair(v0, v1);
        }
        w1f4[tid] = make_uint4(dw[0], dw[1], dw[2], dw[3]);
    } else if (tid < 3072) {                  // layer-2 B frags
        int u2 = tid - 2048;
        int L = u2 & 63, fl = u2 >> 6;
        int nt = fl & 1, k = fl >> 1;
        int quad = L >> 4, col = L & 15;
        unsigned dw[4];
#pragma unroll
        for (int i = 0; i < 4; ++i) {
            int k0 = quad * 8 + 2 * i;
            dw[i] = pk_f16pair(W2[k * 1024 + k0 * 32 + nt * 16 + col],
                               W2[k * 1024 + (k0 + 1) * 32 + nt * 16 + col]);
        }
        w2f4[u2] = make_uint4(dw[0], dw[1], dw[2], dw[3]);
    }

    __syncthreads();
    int eb = b * RBE;
    for (int it = 0; it < (RBE + 255) / 256; ++it) {
        int r = it * 256 + t;
        if (r < RBE) {
            int e = eb + r;
            int d = ei[N_EDGES + e];
            unsigned add = (d & 1) ? (1u << 16) : 1u;
            unsigned old = atomicAdd(&hist[d >> 1], add);
            unsigned rk = (d & 1) ? (old >> 16) : (old & 0xFFFFu);
            rankB[e] = (unsigned short)rk;
            // x mirror: e covers all 800K float2 of x exactly once
            float2 xv = ((const float2*)x)[e];
            xh[e] = pk_f16pair(xv.x, xv.y);
        }
    }
    __syncthreads();
    // dump histogram row (u32 word i = counts for d=2i (lo), d=2i+1 (hi))
    unsigned* cm = (unsigned*)(cntM + (size_t)b * N_NODES);
    for (int i = t; i < N_NODES / 2; i += 256) cm[i] = hist[i];
}

// Per-node exclusive prefix over the 128 block counts -> blkBase, cnt(=deg).
__global__ void colscan_kernel(const unsigned short* __restrict__ cntM,
                               unsigned short* __restrict__ blkBase,
                               int* __restrict__ cnt) {
    int d = blockIdx.x * 256 + threadIdx.x;
    if (d >= N_NODES) return;
    int acc = 0;
#pragma unroll 8
    for (int b = 0; b < RB; ++b) {
        size_t i = (size_t)b * N_NODES + d;
        int v = cntM[i];
        blkBase[i] = (unsigned short)acc;
        acc += v;
    }
    cnt[d] = acc;
}

// Edge pass: branch histogram + bucket scatter of packed 16B payload.
// slotLocal = blkBase[e/RBE][d] + rankB[e]  (no device atomics).
__global__ void pass1_kernel(const int* __restrict__ ei, const float* __restrict__ pos,
                             const float* __restrict__ ea, const float* __restrict__ ew,
                             const unsigned short* __restrict__ rankB,
                             const unsigned short* __restrict__ blkBase,
                             int* __restrict__ bucketCur,
                             uint4* __restrict__ payload) {
    __shared__ int h[K_BR];
    __shared__ int base[K_BR];
    int t = threadIdx.x;
    if (t < K_BR) h[t] = 0;
    __syncthreads();

    int eBase = blockIdx.x * (256 * EPT);
    int sA[EPT], dA[EPT], krA[EPT], slA[EPT];
#pragma unroll
    for (int it = 0; it < EPT; ++it) {
        int e = eBase + it * 256 + t;        // coalesced per sub-iteration
        int s = 0, d = 0, k = 0, rank = 0, slot = 0;
        if (e < N_EDGES) {
            s = ei[e]; d = ei[N_EDGES + e];
            float2 ps2 = ((const float2*)pos)[s];
            float2 pd2 = ((const float2*)pos)[d];
            k = branch_idx(ps2.x - pd2.x, ps2.y - pd2.y);
            rank = atomicAdd(&h[k], 1);
            int bb = e / RBE;
            slot = (int)blkBase[(size_t)bb * N_NODES + d] + (int)rankB[e];
        }
        sA[it] = s; dA[it] = d; krA[it] = (k << 16) | rank; slA[it] = slot;
    }
    __syncthreads();
    if (t < K_BR) base[t] = (h[t] > 0) ? atomicAdd(&bucketCur[t * BSTRIDE], h[t]) : 0;
    __syncthreads();
#pragma unroll
    for (int it = 0; it < EPT; ++it) {
        int e = eBase + it * 256 + t;
        if (e < N_EDGES) {
            int k = krA[it] >> 16, rank = krA[it] & 0xFFFF;
            float4 eav = ((const float4*)ea)[e];
            unsigned ewh = (unsigned)f16bits(ew[e]);
            int idx = (k << 17) + base[k] + rank;
            payload[idx] = make_uint4((unsigned)sA[it] | ((unsigned)dA[it] << 16),
                                      (unsigned)slA[it] | (ewh << 16),
                                      pk_f16pair(eav.x, eav.y),
                                      pk_f16pair(eav.z, eav.w));
        }
    }
}

// single-dispatch decoupled-lookback exclusive scan (R11-proven).
__global__ void scan_kernel(const int* __restrict__ cnt, unsigned* __restrict__ ps,
                            int* __restrict__ nodeStart) {
    __shared__ int s[256];
    __shared__ int sh_off;
    int t = threadIdx.x, b = blockIdx.x;
    int i = b * 256 + t;
    int v = (i < N_NODES) ? cnt[i] : 0;
    s[t] = v;
    __syncthreads();
#pragma unroll
    for (int off = 1; off < 256; off <<= 1) {
        int tmp = (t >= off) ? s[t - off] : 0;
        __syncthreads();
        s[t] += tmp;
        __syncthreads();
    }
    int excl = s[t] - v;
    if (t == 255)
        atomicExch(&ps[b], (unsigned)s[255] | (b == 0 ? FLG_P : FLG_A));
    if (t == 0) sh_off = 0;
    if (t < 64 && b > 0) {   // wave-parallel lookback in wave 0
        int off = 0;
        int base = b - 1;
        for (;;) {
            int idx = base - t;
            unsigned w = 0;
            if (idx >= 0) {
                do { w = atomicOr(&ps[idx], 0u); } while (!(w & (FLG_A | FLG_P)));
            }
            bool isP = (w & FLG_P) != 0;
            unsigned long long pm = __ballot(isP);
            int firstP = pm ? (__ffsll((unsigned long long)pm) - 1) : 64;
            int contrib = (idx >= 0 && t <= firstP) ? (int)(w & VAL_MASK) : 0;
#pragma unroll
            for (int sh = 32; sh > 0; sh >>= 1) contrib += __shfl_down(contrib, sh, 64);
            contrib = __shfl(contrib, 0, 64);
            off += contrib;
            if (firstP < 64 || base - 64 < 0) break;
            base -= 64;
        }
        if (t == 0) sh_off = off;
    }
    __syncthreads();
    if (i < N_NODES) nodeStart[i] = excl + sh_off;
}

// R7 MFMA MLP: no m/out LDS staging. A-frags gathered straight from xh in MFMA
// layout (owner lane's s/d/ea via __shfl); outputs stored straight from the
// accumulators (owner's slot/wh/valid via __shfl). LDS = h-transpose only:
// 1,280B/wave (+32 pad) x 2 waves/block = 2,624B -> occupancy cap ~100%.
__global__ void __launch_bounds__(128, 4) mlp_kernel(
    const uint4* __restrict__ payload,
    const unsigned* __restrict__ xh,
    const uint4* __restrict__ w1f4, const float* __restrict__ b1,
    const uint4* __restrict__ w2f4, const float* __restrict__ b2,
    const int* __restrict__ nodeStart,
    const int* __restrict__ bucketFill,
    unsigned short* __restrict__ fbuf) {
    __shared__ uint4 lds4[164];              // 2,624 B = 2 x (1280 + 32 pad)
    char* hreg = (char*)lds4 + (threadIdx.x >> 6) * 1312;

    int t = blockIdx.x * 128 + threadIdx.x;
    int u = __builtin_amdgcn_readfirstlane(t);
    int k = u >> 17;
    int fill = bucketFill[k * BSTRIDE];
    if ((u & (BCAP - 1)) >= fill) return;   // whole wave past bucket fill
    int rel = t & (BCAP - 1);
    bool valid = rel < fill;
    int idx = (k << 17) + min(rel, fill - 1);  // clamp: pad slots are garbage

    int L = threadIdx.x & 63;
    int quad = L >> 4, col = L & 15;

    uint4 pl = payload[idx];
    int s = (int)(pl.x & 0xFFFFu);
    int d = (int)(pl.x >> 16);
    float whf = (float)__builtin_bit_cast(_Float16, (unsigned short)(pl.y >> 16));
    int slot = valid ? (nodeStart[d] + (int)(pl.y & 0xFFFFu)) : 0;
    int vld = valid ? 1 : 0;

    // ---- B fragments (held in VGPRs; coalesced 16B/lane loads) ----
    half8 B1[2][2], B2[2];
#pragma unroll
    for (int kt = 0; kt < 2; ++kt)
#pragma unroll
        for (int nt = 0; nt < 2; ++nt)
            B1[kt][nt] = __builtin_bit_cast(half8, w1f4[((k * 2 + kt) * 2 + nt) * 64 + L]);
#pragma unroll
    for (int nt = 0; nt < 2; ++nt)
        B2[nt] = __builtin_bit_cast(half8, w2f4[(k * 2 + nt) * 64 + L]);
    float b1o0 = b1[k * 32 + col],      b1o1 = b1[k * 32 + 16 + col];
    float b2o0 = b2[k * 32 + col],      b2o1 = b2[k * 32 + 16 + col];

#pragma unroll
    for (int mt = 0; mt < 4; ++mt) {
        // ---- A-frag: lane (quad,col) holds row er=mt*16+col, k=quad*8..+8 ----
        int erA = mt * 16 + col;
        int sA = __shfl(s, erA, 64);
        int dAi = __shfl(d, erA, 64);
        unsigned zA = (unsigned)__shfl((int)pl.z, erA, 64);
        unsigned wA = (unsigned)__shfl((int)pl.w, erA, 64);
        uint4 xjv = ((const uint4*)xh)[4 * (size_t)sA + quad];
        uint4 xiv = ((const uint4*)xh)[4 * (size_t)dAi + quad];
        half8 a0 = __builtin_bit_cast(half8, xjv) - __builtin_bit_cast(half8, xiv);
        uint4 a1u = make_uint4(quad == 0 ? zA : 0u, quad == 0 ? wA : 0u, 0u, 0u);
        half8 a1 = __builtin_bit_cast(half8, a1u);

        f32x4 c0 = {b1o0, b1o0, b1o0, b1o0};
        f32x4 c1 = {b1o1, b1o1, b1o1, b1o1};
        c0 = MFMA(a0, B1[0][0], c0);
        c0 = MFMA(a1, B1[1][0], c0);
        c1 = MFMA(a0, B1[0][1], c1);
        c1 = MFMA(a1, B1[1][1], c1);
        // ReLU -> h transpose buffer (16 edges x 32 ch f16); wave-synchronous
#pragma unroll
        for (int r = 0; r < 4; ++r) {
            int er = quad * 4 + r;
            *(unsigned short*)(hreg + er * 80 + col * 2)        = f16bits(fmaxf(c0[r], 0.0f));
            *(unsigned short*)(hreg + er * 80 + (16 + col) * 2) = f16bits(fmaxf(c1[r], 0.0f));
        }
        // layer 2
        half8 ah = __builtin_bit_cast(half8, *(const uint4*)(hreg + col * 80 + quad * 16));
        f32x4 d0 = {b2o0, b2o0, b2o0, b2o0};
        f32x4 d1 = {b2o1, b2o1, b2o1, b2o1};
        d0 = MFMA(ah, B2[0], d0);
        d1 = MFMA(ah, B2[1], d1);
        // ---- direct store: lane holds ch col / col+16 of edge mt*16+quad*4+r ----
#pragma unroll
        for (int r = 0; r < 4; ++r) {
            int erC = mt * 16 + quad * 4 + r;
            int slC = __shfl(slot, erC, 64);
            float wC = __shfl(whf, erC, 64);
            int vC = __shfl(vld, erC, 64);
            unsigned short v0 = f16bits(fmaxf(d0[r], 0.0f) * wC);
            unsigned short v1 = f16bits(fmaxf(d1[r], 0.0f) * wC);
            if (vC) {
                unsigned short* orow = fbuf + 32 * (size_t)slC;
                orow[col] = v0;
                orow[16 + col] = v1;
            }
        }
    }
}

// 4 channels per thread: uint2 read = 4 f16; 8 threads/node cover a 64B row.
__global__ void agg_kernel(const unsigned short* __restrict__ fbuf,
                           const int* __restrict__ nodeStart, const int* __restrict__ deg,
                           const float* __restrict__ x, const float* __restrict__ Wr,
                           const float* __restrict__ br, float* __restrict__ out) {
    int t = blockIdx.x * blockDim.x + threadIdx.x;
    if (t >= N_NODES * 8) return;
    int n = t >> 3, g8 = t & 7;          // channels 4*g8 .. 4*g8+3
    int st = nodeStart[n], dg = deg[n];
    const uint2* fb = (const uint2*)fbuf;
    float a0 = 0.0f, a1 = 0.0f, a2 = 0.0f, a3 = 0.0f;
    for (int j = 0; j < dg; ++j) {
        uint2 uu = fb[(size_t)(st + j) * 8 + g8];   // CSR-contiguous stream
        h2 p01 = __builtin_bit_cast(h2, uu.x);
        h2 p23 = __builtin_bit_cast(h2, uu.y);
        a0 += (float)p01.x;
        a1 += (float)p01.y;
        a2 += (float)p23.x;
        a3 += (float)p23.y;
    }
    float inv = 1.0f / (float)max(dg, 1);
    int o = g8 * 4;
    a0 = a0 * inv + br[o];
    a1 = a1 * inv + br[o + 1];
    a2 = a2 * inv + br[o + 2];
    a3 = a3 * inv + br[o + 3];
    const float* xr = x + 32 * (size_t)n;
#pragma unroll
    for (int c = 0; c < 32; ++c) {
        float xv = xr[c];
        a0 = fmaf(xv, Wr[c * 32 + o], a0);
        a1 = fmaf(xv, Wr[c * 32 + o + 1], a1);
        a2 = fmaf(xv, Wr[c * 32 + o + 2], a2);
        a3 = fmaf(xv, Wr[c * 32 + o + 3], a3);
    }
    float4* o4 = (float4*)(out + 32 * (size_t)n + o);
    *o4 = make_float4(a0, a1, a2, a3);
}

extern "C" void kernel_launch(void* const* d_in, const int* in_sizes, int n_in,
                              void* d_out, int out_size, void* d_ws, size_t ws_size,
                              hipStream_t stream) {
    const float* x   = (const float*)d_in[0];
    const float* pos = (const float*)d_in[1];
    const int*   ei  = (const int*)d_in[2];
    const float* ea  = (const float*)d_in[3];
    const float* ew  = (const float*)d_in[4];
    const float* W1  = (const float*)d_in[5];
    const float* b1  = (const float*)d_in[6];
    const float* W2  = (const float*)d_in[7];
    const float* b2  = (const float*)d_in[8];
    const float* Wr  = (const float*)d_in[9];
    const float* br  = (const float*)d_in[10];
    float* out = (float*)d_out;

    char* ws = (char*)d_ws;
    unsigned short* fbuf = (unsigned short*)(ws + 0);
    uint4* payload  = (uint4*)(ws + 51200000);
    int* cnt        = (int*)(ws + 67977216);
    int* bucketCur  = (int*)(ws + 68177216);   // 8 counters @ 4KB stride
    unsigned* psLb  = (unsigned*)(ws + 68209984);
    int* nodeStart  = (int*)(ws + 68210816);
    uint4* w1f4     = (uint4*)(ws + 68410816);
    uint4* w2f4     = (uint4*)(ws + 68443584);
    unsigned* xh    = (unsigned*)(ws + 68459968);
    unsigned short* rankB   = (unsigned short*)(ws + 71659968);
    unsigned short* cntM    = (unsigned short*)(ws + 73259968);
    unsigned short* blkBase = (unsigned short*)(ws + 86059968);

    hipMemsetAsync(bucketCur, 0, 33568, stream);  // bucketCur(strided) + ps

    rank_kernel<<<RB, 256, 0, stream>>>(ei, x, W1, W2, rankB, cntM, xh, w1f4, w2f4);
    colscan_kernel<<<SCAN_BLOCKS, 256, 0, stream>>>(cntM, blkBase, cnt);
    scan_kernel<<<SCAN_BLOCKS, 256, 0, stream>>>(cnt, psLb, nodeStart);
    pass1_kernel<<<P1_BLOCKS, 256, 0, stream>>>(ei, pos, ea, ew, rankB, blkBase,
                                                bucketCur, payload);
    mlp_kernel<<<MLP_SLOTS / 128, 128, 0, stream>>>(payload, xh, w1f4, b1, w2f4, b2,
                                                    nodeStart, bucketCur, fbuf);
    agg_kernel<<<(N_NODES * 8 + 255) / 256, 256, 0, stream>>>(fbuf, nodeStart, cnt,
                                                              x, Wr, br, out);
}

// Round 8
// 185.594 us; speedup vs baseline: 1.7029x; 1.0230x over previous
//
#include <hip/hip_runtime.h>

#define N_NODES 50000
#define N_EDGES 800000
#define K_BR    8
#define BCAP    131072           // per-bucket slot capacity (2^17); mean fill 100K
#define MLP_SLOTS (K_BR * BCAP)  // 1,048,576
#define SCAN_BLOCKS 196          // ceil(50000/256)
#define BSTRIDE 1024             // bucketCur stride in ints (R1: null, kept)
#define EPT 8                    // pass1 edges/thread (R3 structure)
#define P1_BLOCKS 391            // ceil(800000 / 2048)
#define RB 128                   // rank blocks
#define RBE 6250                 // edges per rank block (128*6250 = 800000 exactly)

// R6 accounting: pipeline ~112us vs harness constant ~92us. R7 (mlp de-staging)
// landed: 204 -> 190us total. R8: two safe structural wins —
//  (1) rank: u8-packed LDS hist (4/word; P(count>255) ~ 0 for Binomial(6250,1/50K)),
//      512-thread blocks -> zero/dump loops 98+98 -> 25+25 iters, cntM halved to u8.
//  (2) colscan+scan fused -> one dispatch, no cnt round-trip between them.

typedef _Float16 h2 __attribute__((ext_vector_type(2)));
typedef _Float16 half8 __attribute__((ext_vector_type(8)));
typedef float f32x4 __attribute__((ext_vector_type(4)));

#define MFMA(a, b, c) __builtin_amdgcn_mfma_f32_16x16x32_f16((a), (b), (c), 0, 0, 0)

#define VAL_MASK 0x3FFFFFFFu
#define FLG_A    0x40000000u
#define FLG_P    0x80000000u

// ---------------- workspace layout (bytes) ----------------
// fbuf      : 800,000 x 64 B f16         @ 0           (51,200,000)
// payload   : MLP_SLOTS x 16 B           @ 51,200,000  (16,777,216)
// cnt(deg)  : N ints                     @ 67,977,216  (200,000)  [written by cscan]
// bucketCur : 8 ints @ 4KB stride        @ 68,177,216  (32,768)   [memset 0]
// ps        : 196 uints (lookback)       @ 68,209,984  (800)      [memset 0]
// nodeStart : N ints                     @ 68,210,816  (200,000)
// w1f4      : 2048 uint4 (B-frags L1)    @ 68,410,816  (32,768)
// w2f4      : 1024 uint4 (B-frags L2)    @ 68,443,584  (16,384)
// xh        : 50,000 x 32 f16            @ 68,459,968  (3,200,000)
// rankB     : E u16 (rank within block)  @ 71,659,968  (1,600,000)
// cntM      : [128][50000] u8            @ 73,259,968  (6,400,000)
// blkBase   : [128][50000] u16           @ 86,059,968  (12,800,000)
// total: 98,859,968  (< proven ws floor 109,473,920)

__device__ __forceinline__ int branch_idx(float dx, float dy) {
    return (dx > 0.0f ? 1 : 0) + (dy > 0.0f ? 2 : 0) +
           ((fabsf(dx) - fabsf(dy)) > 0.0f ? 4 : 0);
}

__device__ __forceinline__ unsigned pk_f16pair(float a, float b) {
    h2 p; p.x = (_Float16)a; p.y = (_Float16)b;
    return __builtin_bit_cast(unsigned, p);
}

__device__ __forceinline__ unsigned short f16bits(float a) {
    _Float16 h = (_Float16)a;
    return __builtin_bit_cast(unsigned short, h);
}

// Per-block node histogram + per-edge rank, NO device atomics.
// LDS: 12,500 u32 = four u8 counters per word. 512 threads/block.
// Also absorbs x->f16 mirror and W-frag packing.
__global__ void __launch_bounds__(512) rank_kernel(
    const int* __restrict__ ei, const float* __restrict__ x,
    const float* __restrict__ W1, const float* __restrict__ W2,
    unsigned short* __restrict__ rankB, unsigned char* __restrict__ cntM,
    unsigned* __restrict__ xh, uint4* __restrict__ w1f4, uint4* __restrict__ w2f4) {
    __shared__ unsigned hist[N_NODES / 4];   // 50,000 B
    int t = threadIdx.x, b = blockIdx.x;
    for (int i = t; i < N_NODES / 4; i += 512) hist[i] = 0;

    // W fragments (global tid < 3072)
    int tid = b * 512 + t;
    if (tid < 2048) {                         // layer-1 B frags
        int L = tid & 63, fl = tid >> 6;
        int nt = fl & 1, kt = (fl >> 1) & 1, k = fl >> 2;
        int quad = L >> 4, col = L & 15;
        unsigned dw[4];
#pragma unroll
        for (int i = 0; i < 4; ++i) {
            float v0 = 0.0f, v1 = 0.0f;
            int k0 = kt * 32 + quad * 8 + 2 * i;
            if (k0 < 36)     v0 = W1[k * 1152 + k0 * 32 + nt * 16 + col];
            if (k0 + 1 < 36) v1 = W1[k * 1152 + (k0 + 1) * 32 + nt * 16 + col];
            dw[i] = pk_f16pair(v0, v1);
        }
        w1f4[tid] = make_uint4(dw[0], dw[1], dw[2], dw[3]);
    } else if (tid < 3072) {                  // layer-2 B frags
        int u2 = tid - 2048;
        int L = u2 & 63, fl = u2 >> 6;
        int nt = fl & 1, k = fl >> 1;
        int quad = L >> 4, col = L & 15;
        unsigned dw[4];
#pragma unroll
        for (int i = 0; i < 4; ++i) {
            int k0 = quad * 8 + 2 * i;
            dw[i] = pk_f16pair(W2[k * 1024 + k0 * 32 + nt * 16 + col],
                               W2[k * 1024 + (k0 + 1) * 32 + nt * 16 + col]);
        }
        w2f4[u2] = make_uint4(dw[0], dw[1], dw[2], dw[3]);
    }

    __syncthreads();
    int eb = b * RBE;
    for (int it = 0; it < (RBE + 511) / 512; ++it) {
        int r = it * 512 + t;
        if (r < RBE) {
            int e = eb + r;
            int d = ei[N_EDGES + e];
            unsigned sh = (unsigned)(d & 3) * 8u;
            unsigned old = atomicAdd(&hist[d >> 2], 1u << sh);
            rankB[e] = (unsigned short)((old >> sh) & 0xFFu);
            // x mirror: e covers all 800K float2 of x exactly once
            float2 xv = ((const float2*)x)[e];
            xh[e] = pk_f16pair(xv.x, xv.y);
        }
    }
    __syncthreads();
    // dump histogram row as u32 words (4 nodes per word)
    unsigned* cm = (unsigned*)(cntM + (size_t)b * N_NODES);
    for (int i = t; i < N_NODES / 4; i += 512) cm[i] = hist[i];
}

// Fused per-node column-scan (over RB blocks) + decoupled-lookback exclusive
// scan over nodes. Writes blkBase, cnt(=deg), nodeStart in one dispatch.
__global__ void cscan_kernel(const unsigned char* __restrict__ cntM,
                             unsigned short* __restrict__ blkBase,
                             int* __restrict__ cnt, unsigned* __restrict__ ps,
                             int* __restrict__ nodeStart) {
    __shared__ int s[256];
    __shared__ int sh_off;
    int t = threadIdx.x, b = blockIdx.x;
    int d = b * 256 + t;
    int acc = 0;
    if (d < N_NODES) {
#pragma unroll 8
        for (int blk = 0; blk < RB; ++blk) {
            size_t i = (size_t)blk * N_NODES + d;
            int v = cntM[i];
            blkBase[i] = (unsigned short)acc;
            acc += v;
        }
        cnt[d] = acc;
    }
    int v = (d < N_NODES) ? acc : 0;
    s[t] = v;
    __syncthreads();
#pragma unroll
    for (int off = 1; off < 256; off <<= 1) {
        int tmp = (t >= off) ? s[t - off] : 0;
        __syncthreads();
        s[t] += tmp;
        __syncthreads();
    }
    int excl = s[t] - v;
    if (t == 255)
        atomicExch(&ps[b], (unsigned)s[255] | (b == 0 ? FLG_P : FLG_A));
    if (t == 0) sh_off = 0;
    if (t < 64 && b > 0) {   // wave-parallel lookback in wave 0
        int off = 0;
        int base = b - 1;
        for (;;) {
            int idx = base - t;
            unsigned w = 0;
            if (idx >= 0) {
                do { w = atomicOr(&ps[idx], 0u); } while (!(w & (FLG_A | FLG_P)));
            }
            bool isP = (w & FLG_P) != 0;
            unsigned long long pm = __ballot(isP);
            int firstP = pm ? (__ffsll((unsigned long long)pm) - 1) : 64;
            int contrib = (idx >= 0 && t <= firstP) ? (int)(w & VAL_MASK) : 0;
#pragma unroll
            for (int sh = 32; sh > 0; sh >>= 1) contrib += __shfl_down(contrib, sh, 64);
            contrib = __shfl(contrib, 0, 64);
            off += contrib;
            if (firstP < 64 || base - 64 < 0) break;
            base -= 64;
        }
        if (t == 0) sh_off = off;
    }
    __syncthreads();
    if (d < N_NODES) nodeStart[d] = excl + sh_off;
}

// Edge pass: branch histogram + bucket scatter of packed 16B payload.
// slotLocal = blkBase[e/RBE][d] + rankB[e]  (no device atomics).
__global__ void pass1_kernel(const int* __restrict__ ei, const float* __restrict__ pos,
                             const float* __restrict__ ea, const float* __restrict__ ew,
                             const unsigned short* __restrict__ rankB,
                             const unsigned short* __restrict__ blkBase,
                             int* __restrict__ bucketCur,
                             uint4* __restrict__ payload) {
    __shared__ int h[K_BR];
    __shared__ int base[K_BR];
    int t = threadIdx.x;
    if (t < K_BR) h[t] = 0;
    __syncthreads();

    int eBase = blockIdx.x * (256 * EPT);
    int sA[EPT], dA[EPT], krA[EPT], slA[EPT];
#pragma unroll
    for (int it = 0; it < EPT; ++it) {
        int e = eBase + it * 256 + t;        // coalesced per sub-iteration
        int s = 0, d = 0, k = 0, rank = 0, slot = 0;
        if (e < N_EDGES) {
            s = ei[e]; d = ei[N_EDGES + e];
            float2 ps2 = ((const float2*)pos)[s];
            float2 pd2 = ((const float2*)pos)[d];
            k = branch_idx(ps2.x - pd2.x, ps2.y - pd2.y);
            rank = atomicAdd(&h[k], 1);
            int bb = e / RBE;
            slot = (int)blkBase[(size_t)bb * N_NODES + d] + (int)rankB[e];
        }
        sA[it] = s; dA[it] = d; krA[it] = (k << 16) | rank; slA[it] = slot;
    }
    __syncthreads();
    if (t < K_BR) base[t] = (h[t] > 0) ? atomicAdd(&bucketCur[t * BSTRIDE], h[t]) : 0;
    __syncthreads();
#pragma unroll
    for (int it = 0; it < EPT; ++it) {
        int e = eBase + it * 256 + t;
        if (e < N_EDGES) {
            int k = krA[it] >> 16, rank = krA[it] & 0xFFFF;
            float4 eav = ((const float4*)ea)[e];
            unsigned ewh = (unsigned)f16bits(ew[e]);
            int idx = (k << 17) + base[k] + rank;
            payload[idx] = make_uint4((unsigned)sA[it] | ((unsigned)dA[it] << 16),
                                      (unsigned)slA[it] | (ewh << 16),
                                      pk_f16pair(eav.x, eav.y),
                                      pk_f16pair(eav.z, eav.w));
        }
    }
}

// R7 MFMA MLP: no m/out LDS staging. A-frags gathered straight from xh in MFMA
// layout (owner lane's s/d/ea via __shfl); outputs stored straight from the
// accumulators (owner's slot/wh/valid via __shfl). LDS = h-transpose only.
__global__ void __launch_bounds__(128, 4) mlp_kernel(
    const uint4* __restrict__ payload,
    const unsigned* __restrict__ xh,
    const uint4* __restrict__ w1f4, const float* __restrict__ b1,
    const uint4* __restrict__ w2f4, const float* __restrict__ b2,
    const int* __restrict__ nodeStart,
    const int* __restrict__ bucketFill,
    unsigned short* __restrict__ fbuf) {
    __shared__ uint4 lds4[164];              // 2,624 B = 2 x (1280 + 32 pad)
    char* hreg = (char*)lds4 + (threadIdx.x >> 6) * 1312;

    int t = blockIdx.x * 128 + threadIdx.x;
    int u = __builtin_amdgcn_readfirstlane(t);
    int k = u >> 17;
    int fill = bucketFill[k * BSTRIDE];
    if ((u & (BCAP - 1)) >= fill) return;   // whole wave past bucket fill
    int rel = t & (BCAP - 1);
    bool valid = rel < fill;
    int idx = (k << 17) + min(rel, fill - 1);  // clamp: pad slots are garbage

    int L = threadIdx.x & 63;
    int quad = L >> 4, col = L & 15;

    uint4 pl = payload[idx];
    int s = (int)(pl.x & 0xFFFFu);
    int d = (int)(pl.x >> 16);
    float whf = (float)__builtin_bit_cast(_Float16, (unsigned short)(pl.y >> 16));
    int slot = valid ? (nodeStart[d] + (int)(pl.y & 0xFFFFu)) : 0;
    int vld = valid ? 1 : 0;

    // ---- B fragments (held in VGPRs; coalesced 16B/lane loads) ----
    half8 B1[2][2], B2[2];
#pragma unroll
    for (int kt = 0; kt < 2; ++kt)
#pragma unroll
        for (int nt = 0; nt < 2; ++nt)
            B1[kt][nt] = __builtin_bit_cast(half8, w1f4[((k * 2 + kt) * 2 + nt) * 64 + L]);
#pragma unroll
    for (int nt = 0; nt < 2; ++nt)
        B2[nt] = __builtin_bit_cast(half8, w2f4[(k * 2 + nt) * 64 + L]);
    float b1o0 = b1[k * 32 + col],      b1o1 = b1[k * 32 + 16 + col];
    float b2o0 = b2[k * 32 + col],      b2o1 = b2[k * 32 + 16 + col];

#pragma unroll
    for (int mt = 0; mt < 4; ++mt) {
        // ---- A-frag: lane (quad,col) holds row er=mt*16+col, k=quad*8..+8 ----
        int erA = mt * 16 + col;
        int sA = __shfl(s, erA, 64);
        int dAi = __shfl(d, erA, 64);
        unsigned zA = (unsigned)__shfl((int)pl.z, erA, 64);
        unsigned wA = (unsigned)__shfl((int)pl.w, erA, 64);
        uint4 xjv = ((const uint4*)xh)[4 * (size_t)sA + quad];
        uint4 xiv = ((const uint4*)xh)[4 * (size_t)dAi + quad];
        half8 a0 = __builtin_bit_cast(half8, xjv) - __builtin_bit_cast(half8, xiv);
        uint4 a1u = make_uint4(quad == 0 ? zA : 0u, quad == 0 ? wA : 0u, 0u, 0u);
        half8 a1 = __builtin_bit_cast(half8, a1u);

        f32x4 c0 = {b1o0, b1o0, b1o0, b1o0};
        f32x4 c1 = {b1o1, b1o1, b1o1, b1o1};
        c0 = MFMA(a0, B1[0][0], c0);
        c0 = MFMA(a1, B1[1][0], c0);
        c1 = MFMA(a0, B1[0][1], c1);
        c1 = MFMA(a1, B1[1][1], c1);
        // ReLU -> h transpose buffer (16 edges x 32 ch f16); wave-synchronous
#pragma unroll
        for (int r = 0; r < 4; ++r) {
            int er = quad * 4 + r;
            *(unsigned short*)(hreg + er * 80 + col * 2)        = f16bits(fmaxf(c0[r], 0.0f));
            *(unsigned short*)(hreg + er * 80 + (16 + col) * 2) = f16bits(fmaxf(c1[r], 0.0f));
        }
        // layer 2
        half8 ah = __builtin_bit_cast(half8, *(const uint4*)(hreg + col * 80 + quad * 16));
        f32x4 d0 = {b2o0, b2o0, b2o0, b2o0};
        f32x4 d1 = {b2o1, b2o1, b2o1, b2o1};
        d0 = MFMA(ah, B2[0], d0);
        d1 = MFMA(ah, B2[1], d1);
        // ---- direct store: lane holds ch col / col+16 of edge mt*16+quad*4+r ----
#pragma unroll
        for (int r = 0; r < 4; ++r) {
            int erC = mt * 16 + quad * 4 + r;
            int slC = __shfl(slot, erC, 64);
            float wC = __shfl(whf, erC, 64);
            int vC = __shfl(vld, erC, 64);
            unsigned short v0 = f16bits(fmaxf(d0[r], 0.0f) * wC);
            unsigned short v1 = f16bits(fmaxf(d1[r], 0.0f) * wC);
            if (vC) {
                unsigned short* orow = fbuf + 32 * (size_t)slC;
                orow[col] = v0;
                orow[16 + col] = v1;
            }
        }
    }
}

// 4 channels per thread: uint2 read = 4 f16; 8 threads/node cover a 64B row.
__global__ void agg_kernel(const unsigned short* __restrict__ fbuf,
                           const int* __restrict__ nodeStart, const int* __restrict__ deg,
                           const float* __restrict__ x, const float* __restrict__ Wr,
                           const float* __restrict__ br, float* __restrict__ out) {
    int t = blockIdx.x * blockDim.x + threadIdx.x;
    if (t >= N_NODES * 8) return;
    int n = t >> 3, g8 = t & 7;          // channels 4*g8 .. 4*g8+3
    int st = nodeStart[n], dg = deg[n];
    const uint2* fb = (const uint2*)fbuf;
    float a0 = 0.0f, a1 = 0.0f, a2 = 0.0f, a3 = 0.0f;
    for (int j = 0; j < dg; ++j) {
        uint2 uu = fb[(size_t)(st + j) * 8 + g8];   // CSR-contiguous stream
        h2 p01 = __builtin_bit_cast(h2, uu.x);
        h2 p23 = __builtin_bit_cast(h2, uu.y);
        a0 += (float)p01.x;
        a1 += (float)p01.y;
        a2 += (float)p23.x;
        a3 += (float)p23.y;
    }
    float inv = 1.0f / (float)max(dg, 1);
    int o = g8 * 4;
    a0 = a0 * inv + br[o];
    a1 = a1 * inv + br[o + 1];
    a2 = a2 * inv + br[o + 2];
    a3 = a3 * inv + br[o + 3];
    const float* xr = x + 32 * (size_t)n;
#pragma unroll
    for (int c = 0; c < 32; ++c) {
        float xv = xr[c];
        a0 = fmaf(xv, Wr[c * 32 + o], a0);
        a1 = fmaf(xv, Wr[c * 32 + o + 1], a1);
        a2 = fmaf(xv, Wr[c * 32 + o + 2], a2);
        a3 = fmaf(xv, Wr[c * 32 + o + 3], a3);
    }
    float4* o4 = (float4*)(out + 32 * (size_t)n + o);
    *o4 = make_float4(a0, a1, a2, a3);
}

extern "C" void kernel_launch(void* const* d_in, const int* in_sizes, int n_in,
                              void* d_out, int out_size, void* d_ws, size_t ws_size,
                              hipStream_t stream) {
    const float* x   = (const float*)d_in[0];
    const float* pos = (const float*)d_in[1];
    const int*   ei  = (const int*)d_in[2];
    const float* ea  = (const float*)d_in[3];
    const float* ew  = (const float*)d_in[4];
    const float* W1  = (const float*)d_in[5];
    const float* b1  = (const float*)d_in[6];
    const float* W2  = (const float*)d_in[7];
    const float* b2  = (const float*)d_in[8];
    const float* Wr  = (const float*)d_in[9];
    const float* br  = (const float*)d_in[10];
    float* out = (float*)d_out;

    char* ws = (char*)d_ws;
    unsigned short* fbuf = (unsigned short*)(ws + 0);
    uint4* payload  = (uint4*)(ws + 51200000);
    int* cnt        = (int*)(ws + 67977216);
    int* bucketCur  = (int*)(ws + 68177216);   // 8 counters @ 4KB stride
    unsigned* psLb  = (unsigned*)(ws + 68209984);
    int* nodeStart  = (int*)(ws + 68210816);
    uint4* w1f4     = (uint4*)(ws + 68410816);
    uint4* w2f4     = (uint4*)(ws + 68443584);
    unsigned* xh    = (unsigned*)(ws + 68459968);
    unsigned short* rankB = (unsigned short*)(ws + 71659968);
    unsigned char* cntM   = (unsigned char*)(ws + 73259968);
    unsigned short* blkBase = (unsigned short*)(ws + 86059968);

    hipMemsetAsync(bucketCur, 0, 33568, stream);  // bucketCur(strided) + ps

    rank_kernel<<<RB, 512, 0, stream>>>(ei, x, W1, W2, rankB, cntM, xh, w1f4, w2f4);
    cscan_kernel<<<SCAN_BLOCKS, 256, 0, stream>>>(cntM, blkBase, cnt, psLb, nodeStart);
    pass1_kernel<<<P1_BLOCKS, 256, 0, stream>>>(ei, pos, ea, ew, rankB, blkBase,
                                                bucketCur, payload);
    mlp_kernel<<<MLP_SLOTS / 128, 128, 0, stream>>>(payload, xh, w1f4, b1, w2f4, b2,
                                                    nodeStart, bucketCur, fbuf);
    agg_kernel<<<(N_NODES * 8 + 255) / 256, 256, 0, stream>>>(fbuf, nodeStart, cnt,
                                                              x, Wr, br, out);
}